// Round 2
// baseline (714.496 us; speedup 1.0000x reference)
//
#include <hip/hip_runtime.h>
#include <hip/hip_cooperative_groups.h>
#include <math.h>

namespace cg = cooperative_groups;

#define N_NODES 8192
#define CAP 128           // max neighbors/row; Binom(8192,0.004) mean~33 max~56, +self-loop
#define LRELU_ALPHA 0.2f
#define NBLK 1024         // cooperative grid: 4 blocks/CU x 256 CU, co-resident by construction

typedef float v4f __attribute__((ext_vector_type(4)));

// ---------- gemm core on a pre-staged LDS A-tile (8 rows x K), 256 thr ----------
// Wh[r,c] = sum_k A[r,k] W[k,c];  src = Wh·a[0:128];  dst = Wh·a[128:256]
template <int K>
__device__ __forceinline__ void gemm_from_lds(
    int r0, int t, const float* As, const float* __restrict__ W,
    const float* __restrict__ a, float* __restrict__ Wh, float* __restrict__ src,
    float* __restrict__ dst, float (*red)[4][2]) {
  int c = t & 127, half = t >> 7;
  float acc[4] = {0.f, 0.f, 0.f, 0.f};
  const float* Asl = As + (half * 4) * K;
#pragma unroll 8
  for (int k = 0; k < K; k++) {
    float wv = W[k * 128 + c];
#pragma unroll
    for (int r = 0; r < 4; r++) acc[r] += Asl[r * K + k] * wv;
  }
  float as = a[c], ad = a[128 + c];
  int wv_id = t >> 6, lane = t & 63;
#pragma unroll
  for (int r = 0; r < 4; r++) {
    int row = half * 4 + r;
    Wh[(size_t)(r0 + row) * 128 + c] = acc[r];
    float s = acc[r] * as, d = acc[r] * ad;
#pragma unroll
    for (int off = 32; off; off >>= 1) {
      s += __shfl_xor(s, off);
      d += __shfl_xor(d, off);
    }
    if (lane == 0) { red[wv_id][r][0] = s; red[wv_id][r][1] = d; }
  }
  __syncthreads();
  if (t < 8) {
    int wa = (t < 4) ? 0 : 2, rr = t & 3;
    src[r0 + t] = red[wa][rr][0] + red[wa + 1][rr][0];
    dst[r0 + t] = red[wa][rr][1] + red[wa + 1][rr][1];
  }
}

// ---------- GAT aggregate, ONE node per 64-lane wave, zero barriers ----------
__device__ __forceinline__ float2 agg_node_wave(
    int i, int lane, const float* __restrict__ Wh, const float* __restrict__ src,
    const float* __restrict__ dst, const int* __restrict__ idxbuf,
    const int* __restrict__ counts) {
  int c = counts[i];
  float si = src[i];
  int j0 = 0, j1 = 0;
  float e0 = -1e30f, e1 = -1e30f;
  if (lane < c) {
    j0 = idxbuf[(size_t)i * CAP + lane];
    float xv = si + dst[j0];
    e0 = xv > 0.f ? xv : LRELU_ALPHA * xv;
  }
  if (lane + 64 < c) {
    j1 = idxbuf[(size_t)i * CAP + lane + 64];
    float xv = si + dst[j1];
    e1 = xv > 0.f ? xv : LRELU_ALPHA * xv;
  }
  float m = fmaxf(e0, e1);
#pragma unroll
  for (int off = 32; off; off >>= 1) m = fmaxf(m, __shfl_xor(m, off));
  float w0 = (lane < c) ? expf(e0 - m) : 0.f;
  float w1 = (lane + 64 < c) ? expf(e1 - m) : 0.f;
  float s = w0 + w1;
#pragma unroll
  for (int off = 32; off; off >>= 1) s += __shfl_xor(s, off);
  float inv = 1.f / s;
  const float2* Wh2 = (const float2*)Wh;  // row stride 64 float2
  float ax = 0.f, ay = 0.f;
  int cc = c < 64 ? c : 64;
  int k = 0;
  for (; k + 3 < cc; k += 4) {  // 4 independent 8B loads in flight
    float wa = __shfl(w0, k),     wb = __shfl(w0, k + 1);
    float wc_ = __shfl(w0, k + 2), wd = __shfl(w0, k + 3);
    int ja = __shfl(j0, k),     jb = __shfl(j0, k + 1);
    int jc = __shfl(j0, k + 2), jd = __shfl(j0, k + 3);
    float2 va = Wh2[ja * 64 + lane];
    float2 vb = Wh2[jb * 64 + lane];
    float2 vc = Wh2[jc * 64 + lane];
    float2 vd = Wh2[jd * 64 + lane];
    ax += wa * va.x + wb * vb.x + wc_ * vc.x + wd * vd.x;
    ay += wa * va.y + wb * vb.y + wc_ * vc.y + wd * vd.y;
  }
  for (; k < cc; k++) {
    float wk = __shfl(w0, k);
    int jk = __shfl(j0, k);
    float2 v = Wh2[jk * 64 + lane];
    ax += wk * v.x; ay += wk * v.y;
  }
  for (k = 64; k < c; k++) {  // overflow slot: not taken for this data (max c~57)
    float wk = __shfl(w1, k - 64);
    int jk = __shfl(j1, k - 64);
    float2 v = Wh2[jk * 64 + lane];
    ax += wk * v.x; ay += wk * v.y;
  }
  ax *= inv; ay *= inv;
  return make_float2(ax > 0.f ? ax : expf(ax) - 1.f,
                     ay > 0.f ? ay : expf(ay) - 1.f);
}

// ---------- GRU on LDS tiles (x in tile, hprev in hs), writes output ----------
__device__ __forceinline__ void gru_tile(
    int i0, int t, const float* tile, const float* hs, const float* __restrict__ WiT,
    const float* __restrict__ WhT, const float* __restrict__ b_ih,
    const float* __restrict__ b_hh, float* __restrict__ outp) {
  int c = t & 127, half = t >> 7;
  const float* xsl = tile + half * 4 * 128;
  const float* hsl = hs + half * 4 * 128;
  float rg[4], zg[4];
  {
    float ai[4] = {0.f}, ah[4] = {0.f};
#pragma unroll 4
    for (int k = 0; k < 128; k++) {
      float wi = WiT[k * 384 + c], wh = WhT[k * 384 + c];
#pragma unroll
      for (int r = 0; r < 4; r++) { ai[r] += xsl[r * 128 + k] * wi; ah[r] += hsl[r * 128 + k] * wh; }
    }
    float bi = b_ih[c], bh = b_hh[c];
#pragma unroll
    for (int r = 0; r < 4; r++) rg[r] = 1.f / (1.f + expf(-(ai[r] + bi + ah[r] + bh)));
  }
  {
    float ai[4] = {0.f}, ah[4] = {0.f};
#pragma unroll 4
    for (int k = 0; k < 128; k++) {
      float wi = WiT[k * 384 + 128 + c], wh = WhT[k * 384 + 128 + c];
#pragma unroll
      for (int r = 0; r < 4; r++) { ai[r] += xsl[r * 128 + k] * wi; ah[r] += hsl[r * 128 + k] * wh; }
    }
    float bi = b_ih[128 + c], bh = b_hh[128 + c];
#pragma unroll
    for (int r = 0; r < 4; r++) zg[r] = 1.f / (1.f + expf(-(ai[r] + bi + ah[r] + bh)));
  }
  {
    float ai[4] = {0.f}, ah[4] = {0.f};
#pragma unroll 4
    for (int k = 0; k < 128; k++) {
      float wi = WiT[k * 384 + 256 + c], wh = WhT[k * 384 + 256 + c];
#pragma unroll
      for (int r = 0; r < 4; r++) { ai[r] += xsl[r * 128 + k] * wi; ah[r] += hsl[r * 128 + k] * wh; }
    }
    float bi = b_ih[256 + c], bh = b_hh[256 + c];
#pragma unroll
    for (int r = 0; r < 4; r++) {
      float n = tanhf(ai[r] + bi + rg[r] * (ah[r] + bh));
      outp[(size_t)(i0 + half * 4 + r) * 128 + c] =
          (1.f - zg[r]) * n + zg[r] * hsl[r * 128 + c];
    }
  }
}

// ======================= cooperative mega-kernel: 3 phases, 2 grid syncs =======================
__global__ __launch_bounds__(256, 4) void mega(
    const float* __restrict__ adj, int* __restrict__ idxbuf, int* __restrict__ counts,
    const float* __restrict__ x, const float* __restrict__ W1, const float* __restrict__ a1,
    float* __restrict__ Wh1, float* __restrict__ src1, float* __restrict__ dst1,
    const float* __restrict__ Wi, const float* __restrict__ Whm, float* __restrict__ WiT,
    float* __restrict__ WhT, const float* __restrict__ W2, const float* __restrict__ a2,
    float* __restrict__ Wh2, float* __restrict__ src2, float* __restrict__ dst2,
    const float* __restrict__ hprev, const float* __restrict__ b_ih,
    const float* __restrict__ b_hh, float* __restrict__ outp) {
  __shared__ float As[8 * 256];  // 8KB: gemm1 A-tile; later tile(4KB)+hs(4KB)
  __shared__ float red[4][4][2];
  __shared__ int jn[CAP];
  __shared__ int cnt;
  int t = threadIdx.x, b = blockIdx.x;
  cg::grid_group grid = cg::this_grid();

  // ---- phase 0a: GRU weight transpose (blocks 0..63 only, tiny) ----
  if (b < 64) {
    for (int n = b * 256 + t; n < 384 * 128; n += 64 * 256) {
      int r = n >> 7, c = n & 127;
      WiT[c * 384 + r] = Wi[n];
      WhT[c * 384 + r] = Whm[n];
    }
  }
  // ---- phase 0b: gemm1 on x-tile b (8 rows x 256) + src1/dst1 ----
  {
    const float4* Ab4 = (const float4*)(x + (size_t)b * 8 * 256);
    float4* As4 = (float4*)As;
#pragma unroll
    for (int l = t; l < 8 * 256 / 4; l += 256) As4[l] = Ab4[l];
    __syncthreads();
    gemm_from_lds<256>(b * 8, t, As, W1, a1, Wh1, src1, dst1, red);
  }
  // ---- phase 0c: adj scan, rows b*8 .. b*8+7 (NT stream, LDS compaction) ----
  for (int rr = 0; rr < 8; rr++) {
    int row = b * 8 + rr;
    __syncthreads();  // protect jn/cnt reuse across rows (and red from 0b)
    if (t == 0) cnt = 0;
    __syncthreads();
    const v4f* rowp = (const v4f*)(adj + (size_t)row * N_NODES);
    v4f v[8];
#pragma unroll
    for (int u = 0; u < 8; u++) v[u] = __builtin_nontemporal_load(rowp + t + 256 * u);
#pragma unroll
    for (int u = 0; u < 8; u++) {
      int n = (v[u].x > 0.f) + (v[u].y > 0.f) + (v[u].z > 0.f) + (v[u].w > 0.f);
      if (n) {  // ~1.6% of threads
        int p = atomicAdd(&cnt, n);
        int j0 = (t + 256 * u) * 4;
        if (v[u].x > 0.f) { if (p < CAP) jn[p] = j0;     p++; }
        if (v[u].y > 0.f) { if (p < CAP) jn[p] = j0 + 1; p++; }
        if (v[u].z > 0.f) { if (p < CAP) jn[p] = j0 + 2; p++; }
        if (v[u].w > 0.f) { if (p < CAP) jn[p] = j0 + 3; p++; }
      }
    }
    __syncthreads();
    int c = cnt > CAP ? CAP : cnt;
    if (t < c) idxbuf[(size_t)row * CAP + t] = jn[t];
    if (t == 0) counts[row] = c;
  }

  grid.sync();  // all Wh1/src1/dst1/idxbuf/counts/WiT/WhT visible device-wide

  // ---- phase 1: agg1 (8 nodes, wave-per-node) -> LDS x1 tile -> gemm2 ----
  {
    float* tile = As;
    int wv = t >> 6, lane = t & 63;
    int i0 = b * 8;
    float2 r0 = agg_node_wave(i0 + wv, lane, Wh1, src1, dst1, idxbuf, counts);
    float2 r1 = agg_node_wave(i0 + 4 + wv, lane, Wh1, src1, dst1, idxbuf, counts);
    *(float2*)&tile[wv * 128 + 2 * lane] = r0;
    *(float2*)&tile[(4 + wv) * 128 + 2 * lane] = r1;
    __syncthreads();
    gemm_from_lds<128>(i0, t, tile, W2, a2, Wh2, src2, dst2, red);
  }

  grid.sync();  // Wh2/src2/dst2 visible device-wide

  // ---- phase 2: agg2 (8 nodes) -> LDS h_spat tile -> GRU ----
  {
    float* tile = As;
    float* hs = As + 8 * 128;
    ((float4*)hs)[t] = ((const float4*)(hprev + (size_t)b * 8 * 128))[t];
    int wv = t >> 6, lane = t & 63;
    int i0 = b * 8;
    float2 r0 = agg_node_wave(i0 + wv, lane, Wh2, src2, dst2, idxbuf, counts);
    float2 r1 = agg_node_wave(i0 + 4 + wv, lane, Wh2, src2, dst2, idxbuf, counts);
    *(float2*)&tile[wv * 128 + 2 * lane] = r0;
    *(float2*)&tile[(4 + wv) * 128 + 2 * lane] = r1;
    __syncthreads();
    gru_tile(i0, t, tile, hs, WiT, WhT, b_ih, b_hh, outp);
  }
}

// ======================= fallback 3-kernel path (round-1 proven) =======================
__global__ __launch_bounds__(256) void kA(
    const float* __restrict__ adj, int* __restrict__ idxbuf, int* __restrict__ counts,
    const float* __restrict__ x, const float* __restrict__ W1, const float* __restrict__ a1,
    float* __restrict__ Wh1, float* __restrict__ src1, float* __restrict__ dst1,
    const float* __restrict__ Wi, const float* __restrict__ Whm, float* __restrict__ WiT,
    float* __restrict__ WhT) {
  __shared__ float As[8 * 256];
  __shared__ float red[4][4][2];
  __shared__ int jn[CAP];
  __shared__ int cnt;
  int t = threadIdx.x, b = blockIdx.x;
  if (b < N_NODES) {
    if (t == 0) cnt = 0;
    __syncthreads();
    const v4f* row = (const v4f*)(adj + (size_t)b * N_NODES);
    v4f v[8];
#pragma unroll
    for (int u = 0; u < 8; u++) v[u] = __builtin_nontemporal_load(row + t + 256 * u);
#pragma unroll
    for (int u = 0; u < 8; u++) {
      int n = (v[u].x > 0.f) + (v[u].y > 0.f) + (v[u].z > 0.f) + (v[u].w > 0.f);
      if (n) {
        int p = atomicAdd(&cnt, n);
        int j0 = (t + 256 * u) * 4;
        if (v[u].x > 0.f) { if (p < CAP) jn[p] = j0;     p++; }
        if (v[u].y > 0.f) { if (p < CAP) jn[p] = j0 + 1; p++; }
        if (v[u].z > 0.f) { if (p < CAP) jn[p] = j0 + 2; p++; }
        if (v[u].w > 0.f) { if (p < CAP) jn[p] = j0 + 3; p++; }
      }
    }
    __syncthreads();
    int c = cnt > CAP ? CAP : cnt;
    if (t < c) idxbuf[(size_t)b * CAP + t] = jn[t];
    if (t == 0) counts[b] = c;
  } else if (b < N_NODES + 1024) {
    int tile = b - N_NODES;
    const float4* Ab4 = (const float4*)(x + (size_t)tile * 8 * 256);
    float4* As4 = (float4*)As;
#pragma unroll
    for (int l = t; l < 8 * 256 / 4; l += 256) As4[l] = Ab4[l];
    __syncthreads();
    gemm_from_lds<256>(tile * 8, t, As, W1, a1, Wh1, src1, dst1, red);
  } else {
    for (int n = (b - N_NODES - 1024) * 256 + t; n < 384 * 128; n += 64 * 256) {
      int r = n >> 7, c = n & 127;
      WiT[c * 384 + r] = Wi[n];
      WhT[c * 384 + r] = Whm[n];
    }
  }
}

__global__ __launch_bounds__(256) void kB(
    const float* __restrict__ Wh1, const float* __restrict__ src1,
    const float* __restrict__ dst1, const int* __restrict__ idxbuf,
    const int* __restrict__ counts, const float* __restrict__ W2, const float* __restrict__ a2,
    float* __restrict__ Wh2, float* __restrict__ src2, float* __restrict__ dst2) {
  __shared__ float tile[8 * 128];
  __shared__ float red[4][4][2];
  int t = threadIdx.x, b = blockIdx.x;
  int i0 = b * 8;
  int wv = t >> 6, lane = t & 63;
  float2 r0 = agg_node_wave(i0 + wv, lane, Wh1, src1, dst1, idxbuf, counts);
  *(float2*)&tile[wv * 128 + 2 * lane] = r0;
  float2 r1 = agg_node_wave(i0 + 4 + wv, lane, Wh1, src1, dst1, idxbuf, counts);
  *(float2*)&tile[(4 + wv) * 128 + 2 * lane] = r1;
  __syncthreads();
  gemm_from_lds<128>(i0, t, tile, W2, a2, Wh2, src2, dst2, red);
}

__global__ __launch_bounds__(256) void kC(
    const float* __restrict__ Wh2, const float* __restrict__ src2,
    const float* __restrict__ dst2, const int* __restrict__ idxbuf,
    const int* __restrict__ counts, const float* __restrict__ hprev,
    const float* __restrict__ WiT, const float* __restrict__ WhT,
    const float* __restrict__ b_ih, const float* __restrict__ b_hh, float* __restrict__ outp) {
  __shared__ float tile[8 * 128];
  __shared__ float hs[8 * 128];
  int t = threadIdx.x, b = blockIdx.x;
  int i0 = b * 8;
  ((float4*)hs)[t] = ((const float4*)(hprev + (size_t)i0 * 128))[t];
  int wv = t >> 6, lane = t & 63;
  float2 r0 = agg_node_wave(i0 + wv, lane, Wh2, src2, dst2, idxbuf, counts);
  *(float2*)&tile[wv * 128 + 2 * lane] = r0;
  float2 r1 = agg_node_wave(i0 + 4 + wv, lane, Wh2, src2, dst2, idxbuf, counts);
  *(float2*)&tile[(4 + wv) * 128 + 2 * lane] = r1;
  __syncthreads();
  gru_tile(i0, t, tile, hs, WiT, WhT, b_ih, b_hh, outp);
}

extern "C" void kernel_launch(void* const* d_in, const int* in_sizes, int n_in,
                              void* d_out, int out_size, void* d_ws, size_t ws_size,
                              hipStream_t stream) {
  const float* x     = (const float*)d_in[0];
  const float* adj   = (const float*)d_in[1];
  const float* hprev = (const float*)d_in[2];
  const float* W1    = (const float*)d_in[3];
  const float* a1    = (const float*)d_in[4];
  const float* W2    = (const float*)d_in[5];
  const float* a2    = (const float*)d_in[6];
  const float* Wi    = (const float*)d_in[7];
  const float* Whm   = (const float*)d_in[8];
  const float* b_ih  = (const float*)d_in[9];
  const float* b_hh  = (const float*)d_in[10];
  float* outp = (float*)d_out;

  char* p = (char*)d_ws;
  float* Wh1    = (float*)p; p += (size_t)N_NODES * 128 * 4;
  float* Wh2    = (float*)p; p += (size_t)N_NODES * 128 * 4;
  float* src1   = (float*)p; p += (size_t)N_NODES * 4;
  float* dst1   = (float*)p; p += (size_t)N_NODES * 4;
  float* src2   = (float*)p; p += (size_t)N_NODES * 4;
  float* dst2   = (float*)p; p += (size_t)N_NODES * 4;
  float* WiT    = (float*)p; p += (size_t)384 * 128 * 4;
  float* WhT    = (float*)p; p += (size_t)384 * 128 * 4;
  int*   counts = (int*)p;   p += (size_t)N_NODES * 4;
  int*   idxbuf = (int*)p;   p += (size_t)N_NODES * CAP * 4;

  void* kargs[] = {
      (void*)&adj, (void*)&idxbuf, (void*)&counts, (void*)&x, (void*)&W1, (void*)&a1,
      (void*)&Wh1, (void*)&src1, (void*)&dst1, (void*)&Wi, (void*)&Whm, (void*)&WiT,
      (void*)&WhT, (void*)&W2, (void*)&a2, (void*)&Wh2, (void*)&src2, (void*)&dst2,
      (void*)&hprev, (void*)&b_ih, (void*)&b_hh, (void*)&outp};
  hipError_t e = hipLaunchCooperativeKernel((void*)mega, dim3(NBLK), dim3(256), kargs, 0, stream);
  if (e != hipSuccess) {
    // fallback: proven 3-kernel path
    kA<<<N_NODES + 1024 + 64, 256, 0, stream>>>(adj, idxbuf, counts, x, W1, a1, Wh1, src1, dst1,
                                                Wi, Whm, WiT, WhT);
    kB<<<N_NODES / 8, 256, 0, stream>>>(Wh1, src1, dst1, idxbuf, counts, W2, a2, Wh2, src2, dst2);
    kC<<<N_NODES / 8, 256, 0, stream>>>(Wh2, src2, dst2, idxbuf, counts, hprev, WiT, WhT, b_ih,
                                        b_hh, outp);
  }
}

// Round 3
// 432.204 us; speedup vs baseline: 1.6531x; 1.6531x over previous
//
#include <hip/hip_runtime.h>
#include <math.h>

#define N_NODES 8192
#define CAP 128           // max neighbors/row; Binom(8192,0.004) mean~33 max~56, +self-loop
#define LRELU_ALPHA 0.2f

typedef float v4f __attribute__((ext_vector_type(4)));

// ---------- gemm core on a pre-staged LDS A-tile (8 rows x K), 256 thr ----------
// Wh[r,c] = sum_k A[r,k] W[k,c];  src = Wh·a[0:128];  dst = Wh·a[128:256]
// LDS reads vectorized to ds_read_b128 (broadcast rows), 4x fewer LDS instrs.
template <int K>
__device__ __forceinline__ void gemm_from_lds(
    int r0, int t, const float* As, const float* __restrict__ W,
    const float* __restrict__ a, float* __restrict__ Wh, float* __restrict__ src,
    float* __restrict__ dst, float (*red)[4][2]) {
  int c = t & 127, half = t >> 7;
  float acc[4] = {0.f, 0.f, 0.f, 0.f};
  const float* Asl = As + (half * 4) * K;
#pragma unroll 2
  for (int k = 0; k < K; k += 4) {
    float w0 = W[(k + 0) * 128 + c];
    float w1 = W[(k + 1) * 128 + c];
    float w2 = W[(k + 2) * 128 + c];
    float w3 = W[(k + 3) * 128 + c];
#pragma unroll
    for (int r = 0; r < 4; r++) {
      float4 av = *(const float4*)&Asl[r * K + k];
      acc[r] += av.x * w0 + av.y * w1 + av.z * w2 + av.w * w3;
    }
  }
  float as = a[c], ad = a[128 + c];
  int wv_id = t >> 6, lane = t & 63;
#pragma unroll
  for (int r = 0; r < 4; r++) {
    int row = half * 4 + r;
    Wh[(size_t)(r0 + row) * 128 + c] = acc[r];
    float s = acc[r] * as, d = acc[r] * ad;
#pragma unroll
    for (int off = 32; off; off >>= 1) {
      s += __shfl_xor(s, off);
      d += __shfl_xor(d, off);
    }
    if (lane == 0) { red[wv_id][r][0] = s; red[wv_id][r][1] = d; }
  }
  __syncthreads();
  if (t < 8) {
    int wa = (t < 4) ? 0 : 2, rr = t & 3;
    src[r0 + t] = red[wa][rr][0] + red[wa + 1][rr][0];
    dst[r0 + t] = red[wa][rr][1] + red[wa + 1][rr][1];
  }
}

// ---------- GAT aggregate, ONE node per 64-lane wave, zero barriers ----------
// Softmax in registers via shuffles. Gather: 8 independent float2 loads in
// flight per round; rounds are zero-weight padded (lanes >= c hold w0=0, j0=0)
// so the loop is branch-free.
__device__ __forceinline__ float2 agg_node_wave(
    int i, int lane, const float* __restrict__ Wh, const float* __restrict__ src,
    const float* __restrict__ dst, const int* __restrict__ idxbuf,
    const int* __restrict__ counts) {
  int c = counts[i];
  float si = src[i];
  int j0 = 0, j1 = 0;
  float e0 = -1e30f, e1 = -1e30f;
  if (lane < c) {
    j0 = idxbuf[(size_t)i * CAP + lane];
    float xv = si + dst[j0];
    e0 = xv > 0.f ? xv : LRELU_ALPHA * xv;
  }
  if (lane + 64 < c) {
    j1 = idxbuf[(size_t)i * CAP + lane + 64];
    float xv = si + dst[j1];
    e1 = xv > 0.f ? xv : LRELU_ALPHA * xv;
  }
  float m = fmaxf(e0, e1);
#pragma unroll
  for (int off = 32; off; off >>= 1) m = fmaxf(m, __shfl_xor(m, off));
  float w0 = (lane < c) ? expf(e0 - m) : 0.f;
  float w1 = (lane + 64 < c) ? expf(e1 - m) : 0.f;
  float s = w0 + w1;
#pragma unroll
  for (int off = 32; off; off >>= 1) s += __shfl_xor(s, off);
  float inv = 1.f / s;
  const float2* Wh2 = (const float2*)Wh;  // row stride 64 float2
  float ax = 0.f, ay = 0.f;
  int cc = c < 64 ? c : 64;
  for (int k = 0; k < cc; k += 8) {  // 8 loads in flight; padded rounds are w=0
    float w_[8]; int j_[8]; float2 v_[8];
#pragma unroll
    for (int q = 0; q < 8; q++) { w_[q] = __shfl(w0, k + q); j_[q] = __shfl(j0, k + q); }
#pragma unroll
    for (int q = 0; q < 8; q++) v_[q] = Wh2[(size_t)j_[q] * 64 + lane];
#pragma unroll
    for (int q = 0; q < 8; q++) { ax += w_[q] * v_[q].x; ay += w_[q] * v_[q].y; }
  }
  if (c > 64) {  // overflow slot: not taken for this data (max c~57)
    for (int k = 64; k < c; k++) {
      float wk = __shfl(w1, k - 64);
      int jk = __shfl(j1, k - 64);
      float2 v = Wh2[(size_t)jk * 64 + lane];
      ax += wk * v.x; ay += wk * v.y;
    }
  }
  ax *= inv; ay *= inv;
  return make_float2(ax > 0.f ? ax : expf(ax) - 1.f,
                     ay > 0.f ? ay : expf(ay) - 1.f);
}

// ---------- GRU on LDS tiles: 3 gates fused in ONE k-loop, float4 LDS reads ----------
// x/h tiles read once (not 3x); 256 ds_read_b128 replace 3072 ds_read_b32.
__device__ __forceinline__ void gru_tile(
    int i0, int t, const float* tile, const float* hs, const float* __restrict__ WiT,
    const float* __restrict__ WhT, const float* __restrict__ b_ih,
    const float* __restrict__ b_hh, float* __restrict__ outp) {
  int c = t & 127, half = t >> 7;
  const float* xsl = tile + half * 4 * 128;
  const float* hsl = hs + half * 4 * 128;
  float ai[3][4] = {{0.f}}, ah[3][4] = {{0.f}};
  for (int k = 0; k < 128; k += 4) {
    float4 xv[4], hv[4];
#pragma unroll
    for (int r = 0; r < 4; r++) {
      xv[r] = *(const float4*)&xsl[r * 128 + k];
      hv[r] = *(const float4*)&hsl[r * 128 + k];
    }
#pragma unroll
    for (int g = 0; g < 3; g++) {
      int base = g * 128 + c;
      float wi0 = WiT[(k + 0) * 384 + base], wi1 = WiT[(k + 1) * 384 + base];
      float wi2 = WiT[(k + 2) * 384 + base], wi3 = WiT[(k + 3) * 384 + base];
      float wh0 = WhT[(k + 0) * 384 + base], wh1 = WhT[(k + 1) * 384 + base];
      float wh2 = WhT[(k + 2) * 384 + base], wh3 = WhT[(k + 3) * 384 + base];
#pragma unroll
      for (int r = 0; r < 4; r++) {
        ai[g][r] += xv[r].x * wi0 + xv[r].y * wi1 + xv[r].z * wi2 + xv[r].w * wi3;
        ah[g][r] += hv[r].x * wh0 + hv[r].y * wh1 + hv[r].z * wh2 + hv[r].w * wh3;
      }
    }
  }
  float bi0 = b_ih[c], bi1 = b_ih[128 + c], bi2 = b_ih[256 + c];
  float bh0 = b_hh[c], bh1 = b_hh[128 + c], bh2 = b_hh[256 + c];
#pragma unroll
  for (int r = 0; r < 4; r++) {
    float rg = 1.f / (1.f + expf(-(ai[0][r] + bi0 + ah[0][r] + bh0)));
    float zg = 1.f / (1.f + expf(-(ai[1][r] + bi1 + ah[1][r] + bh1)));
    float n = tanhf(ai[2][r] + bi2 + rg * (ah[2][r] + bh2));
    outp[(size_t)(i0 + half * 4 + r) * 128 + c] =
        (1.f - zg) * n + zg * hsl[r * 128 + c];
  }
}

// ======= kernel A: gemm1 (blocks 0..1023) || transpose (..1087) || adj scan (..9279) ==
// compute blocks first so they overlap the BW-bound scan from t=0.
__global__ __launch_bounds__(256) void kA(
    const float* __restrict__ adj, int* __restrict__ idxbuf, int* __restrict__ counts,
    const float* __restrict__ x, const float* __restrict__ W1, const float* __restrict__ a1,
    float* __restrict__ Wh1, float* __restrict__ src1, float* __restrict__ dst1,
    const float* __restrict__ Wi, const float* __restrict__ Whm, float* __restrict__ WiT,
    float* __restrict__ WhT) {
  __shared__ float As[8 * 256];
  __shared__ float red[4][4][2];
  __shared__ int jn[CAP];
  __shared__ int cnt;
  int t = threadIdx.x, b = blockIdx.x;
  if (b < 1024) {
    const float4* Ab4 = (const float4*)(x + (size_t)b * 8 * 256);
    float4* As4 = (float4*)As;
#pragma unroll
    for (int l = t; l < 8 * 256 / 4; l += 256) As4[l] = Ab4[l];
    __syncthreads();
    gemm_from_lds<256>(b * 8, t, As, W1, a1, Wh1, src1, dst1, red);
  } else if (b < 1088) {
    for (int n = (b - 1024) * 256 + t; n < 384 * 128; n += 64 * 256) {
      int r = n >> 7, c = n & 127;
      WiT[c * 384 + r] = Wi[n];
      WhT[c * 384 + r] = Whm[n];
    }
  } else {
    int row = b - 1088;
    // ---- scan one adj row: 32 KB nontemporal stream, compact into LDS, write list ----
    if (t == 0) cnt = 0;
    __syncthreads();
    const v4f* rowp = (const v4f*)(adj + (size_t)row * N_NODES);
    v4f v[8];
#pragma unroll
    for (int u = 0; u < 8; u++) v[u] = __builtin_nontemporal_load(rowp + t + 256 * u);
#pragma unroll
    for (int u = 0; u < 8; u++) {
      int n = (v[u].x > 0.f) + (v[u].y > 0.f) + (v[u].z > 0.f) + (v[u].w > 0.f);
      if (n) {  // ~1.6% of threads
        int p = atomicAdd(&cnt, n);
        int j0 = (t + 256 * u) * 4;
        if (v[u].x > 0.f) { if (p < CAP) jn[p] = j0;     p++; }
        if (v[u].y > 0.f) { if (p < CAP) jn[p] = j0 + 1; p++; }
        if (v[u].z > 0.f) { if (p < CAP) jn[p] = j0 + 2; p++; }
        if (v[u].w > 0.f) { if (p < CAP) jn[p] = j0 + 3; p++; }
      }
    }
    __syncthreads();
    int c = cnt > CAP ? CAP : cnt;
    if (t < c) idxbuf[(size_t)row * CAP + t] = jn[t];
    if (t == 0) counts[row] = c;
  }
}

// ======= kernel B: agg1 for 8 nodes (4 waves x 2 rounds, barrier-free) -> gemm2+srcdst2 ======
__global__ __launch_bounds__(256) void kB(
    const float* __restrict__ Wh1, const float* __restrict__ src1,
    const float* __restrict__ dst1, const int* __restrict__ idxbuf,
    const int* __restrict__ counts, const float* __restrict__ W2, const float* __restrict__ a2,
    float* __restrict__ Wh2, float* __restrict__ src2, float* __restrict__ dst2) {
  __shared__ float tile[8 * 128];
  __shared__ float red[4][4][2];
  int t = threadIdx.x, b = blockIdx.x;
  int i0 = b * 8;
  int wv = t >> 6, lane = t & 63;
  float2 r0 = agg_node_wave(i0 + wv, lane, Wh1, src1, dst1, idxbuf, counts);
  *(float2*)&tile[wv * 128 + 2 * lane] = r0;
  float2 r1 = agg_node_wave(i0 + 4 + wv, lane, Wh1, src1, dst1, idxbuf, counts);
  *(float2*)&tile[(4 + wv) * 128 + 2 * lane] = r1;
  __syncthreads();
  gemm_from_lds<128>(i0, t, tile, W2, a2, Wh2, src2, dst2, red);
}

// ======= kernel C: agg2 for 8 nodes (barrier-free) -> GRU (h_spat never hits global) ======
__global__ __launch_bounds__(256) void kC(
    const float* __restrict__ Wh2, const float* __restrict__ src2,
    const float* __restrict__ dst2, const int* __restrict__ idxbuf,
    const int* __restrict__ counts, const float* __restrict__ hprev,
    const float* __restrict__ WiT, const float* __restrict__ WhT,
    const float* __restrict__ b_ih, const float* __restrict__ b_hh, float* __restrict__ outp) {
  __shared__ float tile[8 * 128];
  __shared__ float hs[8 * 128];
  int t = threadIdx.x, b = blockIdx.x;
  int i0 = b * 8;
  ((float4*)hs)[t] = ((const float4*)(hprev + (size_t)i0 * 128))[t];
  int wv = t >> 6, lane = t & 63;
  float2 r0 = agg_node_wave(i0 + wv, lane, Wh2, src2, dst2, idxbuf, counts);
  *(float2*)&tile[wv * 128 + 2 * lane] = r0;
  float2 r1 = agg_node_wave(i0 + 4 + wv, lane, Wh2, src2, dst2, idxbuf, counts);
  *(float2*)&tile[(4 + wv) * 128 + 2 * lane] = r1;
  __syncthreads();
  gru_tile(i0, t, tile, hs, WiT, WhT, b_ih, b_hh, outp);
}

extern "C" void kernel_launch(void* const* d_in, const int* in_sizes, int n_in,
                              void* d_out, int out_size, void* d_ws, size_t ws_size,
                              hipStream_t stream) {
  const float* x     = (const float*)d_in[0];
  const float* adj   = (const float*)d_in[1];
  const float* hprev = (const float*)d_in[2];
  const float* W1    = (const float*)d_in[3];
  const float* a1    = (const float*)d_in[4];
  const float* W2    = (const float*)d_in[5];
  const float* a2    = (const float*)d_in[6];
  const float* Wi    = (const float*)d_in[7];
  const float* Whm   = (const float*)d_in[8];
  const float* b_ih  = (const float*)d_in[9];
  const float* b_hh  = (const float*)d_in[10];
  float* outp = (float*)d_out;

  char* p = (char*)d_ws;
  float* Wh1    = (float*)p; p += (size_t)N_NODES * 128 * 4;
  float* Wh2    = (float*)p; p += (size_t)N_NODES * 128 * 4;
  float* src1   = (float*)p; p += (size_t)N_NODES * 4;
  float* dst1   = (float*)p; p += (size_t)N_NODES * 4;
  float* src2   = (float*)p; p += (size_t)N_NODES * 4;
  float* dst2   = (float*)p; p += (size_t)N_NODES * 4;
  float* WiT    = (float*)p; p += (size_t)384 * 128 * 4;
  float* WhT    = (float*)p; p += (size_t)384 * 128 * 4;
  int*   counts = (int*)p;   p += (size_t)N_NODES * 4;
  int*   idxbuf = (int*)p;   p += (size_t)N_NODES * CAP * 4;

  // A: gemm1 + transpose first (compute), adj scan after (BW) -- they co-run
  kA<<<1024 + 64 + N_NODES, 256, 0, stream>>>(adj, idxbuf, counts, x, W1, a1, Wh1, src1, dst1,
                                              Wi, Whm, WiT, WhT);
  // B: agg1 (wave-per-node, 8-deep gather) -> LDS x1 tile -> gemm2+srcdst2
  kB<<<N_NODES / 8, 256, 0, stream>>>(Wh1, src1, dst1, idxbuf, counts, W2, a2, Wh2, src2, dst2);
  // C: agg2 -> LDS h_spat tile -> fused-gate GRU
  kC<<<N_NODES / 8, 256, 0, stream>>>(Wh2, src2, dst2, idxbuf, counts, hprev, WiT, WhT, b_ih,
                                      b_hh, outp);
}